// Round 9
// baseline (1431.209 us; speedup 1.0000x reference)
//
#include <hip/hip_runtime.h>
#include <math.h>
#include <stdint.h>

#define KP 16384
#define IN_DIM 512
#define HD 1024
#define WQ 512      // per-wave LDS survivor queue
#define HOTCAP 1024

typedef _Float16 f16x8 __attribute__((ext_vector_type(8)));
typedef float f32x4 __attribute__((ext_vector_type(4)));

// ---------------- threefry2x32 (JAX key(42) => k0=0, k1=42) ----------------
__device__ __forceinline__ uint32_t rotl(uint32_t x, uint32_t r) {
  return __builtin_amdgcn_alignbit(x, x, 32u - r);
}

// cipher specialized for x0_init=0; input v = i + 42 (= x1 after key add)
__device__ __forceinline__ uint32_t tf_bits(uint32_t x1) {
  const uint32_t ks1 = 42u, ks2 = 42u ^ 0x1BD11BDAu;
  uint32_t x0 = x1;                       // x0(=0) += x1
  x1 = rotl(x1, 13) ^ x0;
  x0 += x1; x1 = rotl(x1, 15) ^ x0;
  x0 += x1; x1 = rotl(x1, 26) ^ x0;
  x0 += x1; x1 = rotl(x1, 6)  ^ x0;
  x0 += ks1; x1 += ks2 + 1u;
  x0 += x1; x1 = rotl(x1, 17) ^ x0;
  x0 += x1; x1 = rotl(x1, 29) ^ x0;
  x0 += x1; x1 = rotl(x1, 16) ^ x0;
  x0 += x1; x1 = rotl(x1, 24) ^ x0;
  x0 += ks2; x1 += 2u;
  x0 += x1; x1 = rotl(x1, 13) ^ x0;
  x0 += x1; x1 = rotl(x1, 15) ^ x0;
  x0 += x1; x1 = rotl(x1, 26) ^ x0;
  x0 += x1; x1 = rotl(x1, 6)  ^ x0;
  x1 += ks1 + 3u;
  x0 += x1; x1 = rotl(x1, 17) ^ x0;
  x0 += x1; x1 = rotl(x1, 29) ^ x0;
  x0 += x1; x1 = rotl(x1, 16) ^ x0;
  x0 += x1; x1 = rotl(x1, 24) ^ x0;
  x0 += ks1; x1 += ks2 + 4u;
  x0 += x1; x1 = rotl(x1, 13) ^ x0;
  x0 += x1; x1 = rotl(x1, 15) ^ x0;
  x0 += x1; x1 = rotl(x1, 26) ^ x0;
  x0 += x1; x1 = rotl(x1, 6)  ^ x0;
  x0 += ks2; x1 += 5u;
  return x0 ^ x1;
}

__device__ __forceinline__ float gumbel_from_bits(uint32_t b) {
  uint32_t ub = (b >> 9) | 0x3f800000u;
  float u = __uint_as_float(ub) - 1.0f;
  u = fmaxf(u, 1.1754943508222875e-38f);
  return -logf(-logf(u));
}

// monotone (g, smaller-c-wins) -> uint64 key for max-reduce argmax
__device__ __forceinline__ unsigned long long pack_key(float g, int c) {
  uint32_t u = __float_as_uint(g);
  u = (u & 0x80000000u) ? ~u : (u | 0x80000000u);
  return ((unsigned long long)u << 32) | (uint32_t)(16383 - c);
}

// ---------------- bias precompute: input_ @ W[1024:,:] + b ----------------
__global__ __launch_bounds__(256) void bias_kernel(
    const float* __restrict__ in,
    const float* __restrict__ wz, const float* __restrict__ bz,
    const float* __restrict__ wr, const float* __restrict__ br,
    const float* __restrict__ wn, const float* __restrict__ bn,
    const float* __restrict__ wobs, const float* __restrict__ bobs,
    float* __restrict__ zb, float* __restrict__ rb,
    float* __restrict__ nb, float* __restrict__ ob) {
  __shared__ float sin_[IN_DIM];
  int t = threadIdx.x;
  for (int i = t; i < IN_DIM; i += 256) sin_[i] = in[i];
  __syncthreads();
  int gid = blockIdx.x * 256 + t;
  if (gid < 1024) {
    float s = bz[gid];
    for (int i = 0; i < IN_DIM; ++i) s = fmaf(sin_[i], wz[(HD + i) * HD + gid], s);
    zb[gid] = s;
  } else if (gid < 2048) {
    int j = gid - 1024;
    float s = br[j];
    for (int i = 0; i < IN_DIM; ++i) s = fmaf(sin_[i], wr[(HD + i) * HD + j], s);
    rb[j] = s;
  } else if (gid < 4096) {
    int j = gid - 2048;
    float s = bn[j];
    for (int i = 0; i < IN_DIM; ++i) s = fmaf(sin_[i], wn[(HD + i) * 2048 + j], s);
    nb[j] = s;
  } else if (gid == 4096) {
    float s = bobs[0];
    for (int i = 0; i < IN_DIM; ++i) s = fmaf(sin_[i], wobs[HD + i], s);
    ob[0] = s;
  }
}

// ---------------- weight transpose + fp16 2-term split (x64 prescale) ------
__global__ __launch_bounds__(256) void splitw_kernel(
    const float* __restrict__ wz, const float* __restrict__ wr,
    const float* __restrict__ wn,
    _Float16* __restrict__ zHi, _Float16* __restrict__ zLo,
    _Float16* __restrict__ rHi, _Float16* __restrict__ rLo,
    _Float16* __restrict__ mHi, _Float16* __restrict__ mLo,
    _Float16* __restrict__ vHi, _Float16* __restrict__ vLo) {
  __shared__ float tile[32][33];
  int m = blockIdx.z;
  const float* src; int ld, cofs; _Float16 *oh, *ol;
  if (m == 0)      { src = wz; ld = 1024; cofs = 0;    oh = zHi; ol = zLo; }
  else if (m == 1) { src = wr; ld = 1024; cofs = 0;    oh = rHi; ol = rLo; }
  else if (m == 2) { src = wn; ld = 2048; cofs = 0;    oh = mHi; ol = mLo; }
  else             { src = wn; ld = 2048; cofs = 1024; oh = vHi; ol = vLo; }
  int k0 = blockIdx.x * 32, n0 = blockIdx.y * 32;
  int tx = threadIdx.x & 31, ty = threadIdx.x >> 5;
#pragma unroll
  for (int i = 0; i < 4; ++i) {
    int k = ty * 4 + i;
    tile[k][tx] = src[(size_t)(k0 + k) * ld + cofs + n0 + tx];
  }
  __syncthreads();
#pragma unroll
  for (int i = 0; i < 4; ++i) {
    int n = ty * 4 + i;
    float v = tile[tx][n] * 64.0f;
    _Float16 h = (_Float16)v;
    _Float16 l = (_Float16)((v - (float)h) * 2048.0f);
    oh[(size_t)(n0 + n) * 1024 + k0 + tx] = h;
    ol[(size_t)(n0 + n) * 1024 + k0 + tx] = l;
  }
}

// ---------------- MFMA split-GEMM #1: z & rh (rh written as fp16 split) ----
#define LDH 40   // halfs per LDS row (32 data + 8 pad); 80B, 16B-multiple

__global__ __launch_bounds__(256, 2) void gemm_zr_mfma(
    const float* __restrict__ A,  // h0: KP x HD fp32 (also epilogue h0)
    const _Float16* __restrict__ BzHi, const _Float16* __restrict__ BzLo,
    const _Float16* __restrict__ BrHi, const _Float16* __restrict__ BrLo,
    const float* __restrict__ zbias, const float* __restrict__ rbias,
    float* __restrict__ zout,
    _Float16* __restrict__ rhh, _Float16* __restrict__ rhl) {
  __shared__ __align__(16) _Float16 Ah[128 * LDH], Al[128 * LDH];
  __shared__ __align__(16) _Float16 B0h[64 * LDH], B0l[64 * LDH];
  __shared__ __align__(16) _Float16 B1h[64 * LDH], B1l[64 * LDH];
  int t = threadIdx.x;
  int row0 = blockIdx.x * 128, col0 = blockIdx.y * 64;
  int wave = t >> 6, lane = t & 63;
  int lr = lane & 15, hh = lane >> 4;
  int WR = (wave >> 1) * 64, WC = (wave & 1) * 32;

  f32x4 acc0[4][2][2] = {};
  f32x4 acc1[4][2][2] = {};

  for (int kb = 0; kb < 1024; kb += 32) {
#pragma unroll
    for (int p = 0; p < 2; ++p) {
      int id = t + p * 256;
      int row = id >> 2, kc = id & 3;
      const float* g = &A[(size_t)(row0 + row) * 1024 + kb + kc * 8];
      float4 v0 = *(const float4*)g;
      float4 v1 = *(const float4*)(g + 4);
      float vv[8] = {v0.x, v0.y, v0.z, v0.w, v1.x, v1.y, v1.z, v1.w};
      f16x8 hi, lo;
#pragma unroll
      for (int j = 0; j < 8; ++j) {
        _Float16 h = (_Float16)vv[j];
        hi[j] = h;
        lo[j] = (_Float16)((vv[j] - (float)h) * 2048.0f);
      }
      *(f16x8*)&Ah[row * LDH + kc * 8] = hi;
      *(f16x8*)&Al[row * LDH + kc * 8] = lo;
    }
    {
      int n = t >> 2, kc = t & 3;
      size_t gofs = (size_t)(col0 + n) * 1024 + kb + kc * 8;
      int lofs = n * LDH + kc * 8;
      *(f16x8*)&B0h[lofs] = *(const f16x8*)&BzHi[gofs];
      *(f16x8*)&B0l[lofs] = *(const f16x8*)&BzLo[gofs];
      *(f16x8*)&B1h[lofs] = *(const f16x8*)&BrHi[gofs];
      *(f16x8*)&B1l[lofs] = *(const f16x8*)&BrLo[gofs];
    }
    __syncthreads();
    f16x8 ah[4], al[4], bh[2][2], bl[2][2];
#pragma unroll
    for (int mt = 0; mt < 4; ++mt) {
      int r = WR + mt * 16 + lr;
      ah[mt] = *(f16x8*)&Ah[r * LDH + hh * 8];
      al[mt] = *(f16x8*)&Al[r * LDH + hh * 8];
    }
#pragma unroll
    for (int nt = 0; nt < 2; ++nt) {
      int c = WC + nt * 16 + lr;
      bh[0][nt] = *(f16x8*)&B0h[c * LDH + hh * 8];
      bl[0][nt] = *(f16x8*)&B0l[c * LDH + hh * 8];
      bh[1][nt] = *(f16x8*)&B1h[c * LDH + hh * 8];
      bl[1][nt] = *(f16x8*)&B1l[c * LDH + hh * 8];
    }
#pragma unroll
    for (int mt = 0; mt < 4; ++mt)
#pragma unroll
      for (int nt = 0; nt < 2; ++nt)
#pragma unroll
        for (int m = 0; m < 2; ++m) {
          acc0[mt][nt][m] = __builtin_amdgcn_mfma_f32_16x16x32_f16(ah[mt], bh[m][nt], acc0[mt][nt][m], 0, 0, 0);
          acc1[mt][nt][m] = __builtin_amdgcn_mfma_f32_16x16x32_f16(ah[mt], bl[m][nt], acc1[mt][nt][m], 0, 0, 0);
          acc1[mt][nt][m] = __builtin_amdgcn_mfma_f32_16x16x32_f16(al[mt], bh[m][nt], acc1[mt][nt][m], 0, 0, 0);
        }
    __syncthreads();
  }
  const float INV = 1.0f / 2048.0f, WS = 1.0f / 64.0f;
#pragma unroll
  for (int mt = 0; mt < 4; ++mt)
#pragma unroll
    for (int nt = 0; nt < 2; ++nt) {
      int col = col0 + WC + nt * 16 + lr;
#pragma unroll
      for (int q = 0; q < 4; ++q) {
        int row = row0 + WR + mt * 16 + hh * 4 + q;
        size_t off = (size_t)row * 1024 + col;
        float vz = (acc0[mt][nt][0][q] + acc1[mt][nt][0][q] * INV) * WS + zbias[col];
        float vr = (acc0[mt][nt][1][q] + acc1[mt][nt][1][q] * INV) * WS + rbias[col];
        float z = 1.0f / (1.0f + expf(-vz));
        float r = 1.0f / (1.0f + expf(-vr));
        float rv = r * A[off];
        zout[off] = z;
        _Float16 rhi = (_Float16)rv;
        rhh[off] = rhi;
        rhl[off] = (_Float16)((rv - (float)rhi) * 2048.0f);
      }
    }
}

// ---------------- MFMA split-GEMM #2: A pre-split fp16; h1 epilogue --------
__global__ __launch_bounds__(256, 2) void gemm_n_mfma(
    const _Float16* __restrict__ Ahg, const _Float16* __restrict__ Alg, // rh split
    const _Float16* __restrict__ BmHi, const _Float16* __restrict__ BmLo,
    const _Float16* __restrict__ BvHi, const _Float16* __restrict__ BvLo,
    const float* __restrict__ nbias,
    const float* __restrict__ h0, const float* __restrict__ eps,
    const float* __restrict__ zbuf, float* __restrict__ h1out) {
  __shared__ __align__(16) _Float16 Ah[128 * LDH], Al[128 * LDH];
  __shared__ __align__(16) _Float16 B0h[64 * LDH], B0l[64 * LDH];
  __shared__ __align__(16) _Float16 B1h[64 * LDH], B1l[64 * LDH];
  int t = threadIdx.x;
  int row0 = blockIdx.x * 128, col0 = blockIdx.y * 64;
  int wave = t >> 6, lane = t & 63;
  int lr = lane & 15, hh = lane >> 4;
  int WR = (wave >> 1) * 64, WC = (wave & 1) * 32;

  f32x4 acc0[4][2][2] = {};
  f32x4 acc1[4][2][2] = {};

  for (int kb = 0; kb < 1024; kb += 32) {
#pragma unroll
    for (int p = 0; p < 2; ++p) {
      int id = t + p * 256;
      int row = id >> 2, kc = id & 3;
      size_t g = (size_t)(row0 + row) * 1024 + kb + kc * 8;
      int lofs = row * LDH + kc * 8;
      *(f16x8*)&Ah[lofs] = *(const f16x8*)&Ahg[g];
      *(f16x8*)&Al[lofs] = *(const f16x8*)&Alg[g];
    }
    {
      int n = t >> 2, kc = t & 3;
      size_t gofs = (size_t)(col0 + n) * 1024 + kb + kc * 8;
      int lofs = n * LDH + kc * 8;
      *(f16x8*)&B0h[lofs] = *(const f16x8*)&BmHi[gofs];
      *(f16x8*)&B0l[lofs] = *(const f16x8*)&BmLo[gofs];
      *(f16x8*)&B1h[lofs] = *(const f16x8*)&BvHi[gofs];
      *(f16x8*)&B1l[lofs] = *(const f16x8*)&BvLo[gofs];
    }
    __syncthreads();
    f16x8 ah[4], al[4], bh[2][2], bl[2][2];
#pragma unroll
    for (int mt = 0; mt < 4; ++mt) {
      int r = WR + mt * 16 + lr;
      ah[mt] = *(f16x8*)&Ah[r * LDH + hh * 8];
      al[mt] = *(f16x8*)&Al[r * LDH + hh * 8];
    }
#pragma unroll
    for (int nt = 0; nt < 2; ++nt) {
      int c = WC + nt * 16 + lr;
      bh[0][nt] = *(f16x8*)&B0h[c * LDH + hh * 8];
      bl[0][nt] = *(f16x8*)&B0l[c * LDH + hh * 8];
      bh[1][nt] = *(f16x8*)&B1h[c * LDH + hh * 8];
      bl[1][nt] = *(f16x8*)&B1l[c * LDH + hh * 8];
    }
#pragma unroll
    for (int mt = 0; mt < 4; ++mt)
#pragma unroll
      for (int nt = 0; nt < 2; ++nt)
#pragma unroll
        for (int m = 0; m < 2; ++m) {
          acc0[mt][nt][m] = __builtin_amdgcn_mfma_f32_16x16x32_f16(ah[mt], bh[m][nt], acc0[mt][nt][m], 0, 0, 0);
          acc1[mt][nt][m] = __builtin_amdgcn_mfma_f32_16x16x32_f16(ah[mt], bl[m][nt], acc1[mt][nt][m], 0, 0, 0);
          acc1[mt][nt][m] = __builtin_amdgcn_mfma_f32_16x16x32_f16(al[mt], bh[m][nt], acc1[mt][nt][m], 0, 0, 0);
        }
    __syncthreads();
  }
  const float INV = 1.0f / 2048.0f, WS = 1.0f / 64.0f;
#pragma unroll
  for (int mt = 0; mt < 4; ++mt)
#pragma unroll
    for (int nt = 0; nt < 2; ++nt) {
      int col = col0 + WC + nt * 16 + lr;
#pragma unroll
      for (int q = 0; q < 4; ++q) {
        int row = row0 + WR + mt * 16 + hh * 4 + q;
        size_t off = (size_t)row * 1024 + col;
        float mu = (acc0[mt][nt][0][q] + acc1[mt][nt][0][q] * INV) * WS + nbias[col];
        float var = (acc0[mt][nt][1][q] + acc1[mt][nt][1][q] * INV) * WS + nbias[1024 + col];
        float sp = fmaxf(var, 0.0f) + log1pf(expf(-fabsf(var)));
        float n = tanhf(mu + eps[off] * sp);
        float z = zbuf[off];
        h1out[off] = (1.0f - z) * n + z * h0[off];
      }
    }
}

// ---------------- score: s = h1@wobs[:1024] + ob + p0 ----------------------
__global__ __launch_bounds__(256) void score_kernel(
    const float* __restrict__ h1, const float* __restrict__ wobs,
    const float* __restrict__ ob, const float* __restrict__ p0,
    float* __restrict__ s) {
  __shared__ float w[HD];
  int t = threadIdx.x;
  for (int i = t; i < HD; i += 256) w[i] = wobs[i];
  __syncthreads();
  int wave = t >> 6, lane = t & 63;
  int row = blockIdx.x * 4 + wave;
  float acc = 0.0f;
  for (int c = lane * 4; c < HD; c += 256) {
    float4 v = *(const float4*)&h1[(size_t)row * HD + c];
    acc = fmaf(v.x, w[c], acc);
    acc = fmaf(v.y, w[c + 1], acc);
    acc = fmaf(v.z, w[c + 2], acc);
    acc = fmaf(v.w, w[c + 3], acc);
  }
#pragma unroll
  for (int off = 32; off; off >>= 1) acc += __shfl_down(acc, off);
  if (lane == 0) s[row] = acc + ob[0] + p0[row];
}

// -------- log_softmax over K + categorical logits + Lmax + hot list --------
__global__ __launch_bounds__(1024) void softmax_kernel(
    const float* __restrict__ s, float* __restrict__ p1v,
    float* __restrict__ logits, float* __restrict__ lmaxp,
    int* __restrict__ hotc, unsigned int* __restrict__ hotn) {
  __shared__ float red[1024];
  int t = threadIdx.x;
  if (t == 0) hotn[0] = 0u;
  float m = -INFINITY;
  for (int k = t; k < KP; k += 1024) m = fmaxf(m, s[k]);
  red[t] = m; __syncthreads();
  for (int o = 512; o; o >>= 1) { if (t < o) red[t] = fmaxf(red[t], red[t + o]); __syncthreads(); }
  m = red[0]; __syncthreads();
  float sum = 0.0f;
  for (int k = t; k < KP; k += 1024) sum += expf(s[k] - m);
  red[t] = sum; __syncthreads();
  for (int o = 512; o; o >>= 1) { if (t < o) red[t] += red[t + o]; __syncthreads(); }
  float ls = logf(red[0]);
  float lmax = logf(0.5f * expf(-ls) + (0.5f / KP));
  float hthr = lmax - 6.0f;
  for (int k = t; k < KP; k += 1024) {
    float p = s[k] - m - ls;
    p1v[k] = p;
    float lg = logf(0.5f * expf(p) + (0.5f / KP));
    logits[k] = lg;
    if (lg > hthr) {
      unsigned int slot = atomicAdd(hotn, 1u);
      if (slot < HOTCAP) hotc[slot] = k;   // SET nondeterministic only if >cap;
    }                                      // affects threshold (perf), not idx
  }
  if (t == 0) lmaxp[0] = lmax;
}

// ---------------- categorical phase A: sample + hot list -> threshold ------
// one wave per row; exact eval of cols 0..255 and hot-list cols
__global__ __launch_bounds__(256) void thr_kernel(
    const float* __restrict__ logits, const float* __restrict__ lmaxp,
    const int* __restrict__ hotc, const unsigned int* __restrict__ hotn,
    uint32_t* __restrict__ sthr, unsigned long long* __restrict__ best) {
  int t = threadIdx.x;
  int wave = t >> 6, lane = t & 63;
  int r = blockIdx.x * 4 + wave;
  uint32_t base = ((uint32_t)r << 14) + 42u;

  unsigned long long key = 0ull;
#pragma unroll
  for (int j = 0; j < 4; ++j) {
    int c = lane + j * 64;
    uint32_t bits = tf_bits(base + (uint32_t)c);
    float g = gumbel_from_bits(bits) + logits[c];
    unsigned long long k2 = pack_key(g, c);
    if (k2 > key) key = k2;
  }
  int hn = (int)hotn[0];
  if (hn > HOTCAP) hn = HOTCAP;
  for (int i = lane; i < hn; i += 64) {
    int c = hotc[i];
    uint32_t bits = tf_bits(base + (uint32_t)c);
    float g = gumbel_from_bits(bits) + logits[c];
    unsigned long long k2 = pack_key(g, c);
    if (k2 > key) key = k2;
  }
#pragma unroll
  for (int off = 32; off; off >>= 1) {
    unsigned long long ok = __shfl_down(key, off);
    if (ok > key) key = ok;
  }
  if (lane == 0) {
    // B0 from packed key (exact float, order-invariant)
    uint32_t u = (uint32_t)(key >> 32);
    u = (u & 0x80000000u) ? (u & 0x7FFFFFFFu) : ~u;
    float B0 = __uint_as_float(u);
    float wth = expf(lmaxp[0] + 1e-3f - B0);
    float omu = -expm1f(-wth);
    float delta = 8388608.0f * omu;
    uint32_t thr;
    if (delta >= 8388592.0f) thr = 0u;
    else {
      thr = 8388608u - (uint32_t)delta;
      thr = (thr > 24u) ? (thr - 24u) : 0u;
    }
    sthr[r] = thr << 9;   // compare raw bits directly
    best[r] = key;
  }
}

// ---------------- categorical phase B: branchless scan, per-wave queues ----
// one block per row; ballot-compacted LDS push (no atomics, no VMEM in loop)
__global__ __launch_bounds__(256) void scan_kernel(
    const uint32_t* __restrict__ sthr, const float* __restrict__ logits,
    const unsigned long long* __restrict__ best, int* __restrict__ idx) {
  __shared__ uint32_t qb[4][WQ];
  __shared__ uint32_t qc[4][WQ];
  __shared__ unsigned long long redw[4];
  int t = threadIdx.x;
  int wave = t >> 6, lane = t & 63;
  int r = blockIdx.x;
  uint32_t thr = sthr[r];
  uint32_t base = ((uint32_t)r << 14) + 42u;

  unsigned long long mykey = 0ull;
  int wcnt = 0;
  for (int it = 0; it < 63; ++it) {
    uint32_t c = 256u + (uint32_t)it * 256u + (uint32_t)t;
    uint32_t bits = tf_bits(base + c);
    bool pass = bits >= thr;
    unsigned long long mball = __ballot(pass);
    if (mball) {
      int pos = __popcll(mball & ((1ull << lane) - 1ull));
      if (pass) {
        int slot = wcnt + pos;
        if (slot < WQ) { qb[wave][slot] = bits; qc[wave][slot] = c; }
        else {  // rare overflow: exact inline eval (deterministic)
          float g = gumbel_from_bits(bits) + logits[c];
          unsigned long long kk = pack_key(g, (int)c);
          if (kk > mykey) mykey = kk;
        }
      }
      wcnt += __popcll(mball);
    }
  }
  // phase 2: exact eval of this wave's queue
  int n = wcnt < WQ ? wcnt : WQ;
  for (int i = lane; i < n; i += 64) {
    float g = gumbel_from_bits(qb[wave][i]) + logits[qc[wave][i]];
    unsigned long long kk = pack_key(g, (int)qc[wave][i]);
    if (kk > mykey) mykey = kk;
  }
#pragma unroll
  for (int off = 32; off; off >>= 1) {
    unsigned long long ok = __shfl_down(mykey, off);
    if (ok > mykey) mykey = ok;
  }
  if (lane == 0) redw[wave] = mykey;
  __syncthreads();
  if (t == 0) {
    unsigned long long k = best[r];   // block owns row r exclusively
    for (int w = 0; w < 4; ++w) if (redw[w] > k) k = redw[w];
    idx[r] = 16383 - (int)(k & 16383ull);
  }
}

// ---------------- resample weights + final p1 ------------------------------
__global__ __launch_bounds__(1024) void resample_kernel(
    const float* __restrict__ p1v, const int* __restrict__ idx,
    float* __restrict__ pn, float* __restrict__ p1out, float* __restrict__ wexp) {
  __shared__ float red[1024];
  int t = threadIdx.x;
  float m = -INFINITY;
  for (int k = t; k < KP; k += 1024) {
    float pv = p1v[idx[k]];
    float w = expf(pv);
    float v = logf(w / (0.5f * w + (0.5f / KP)));
    pn[k] = v;
    m = fmaxf(m, v);
  }
  red[t] = m; __syncthreads();
  for (int o = 512; o; o >>= 1) { if (t < o) red[t] = fmaxf(red[t], red[t + o]); __syncthreads(); }
  m = red[0]; __syncthreads();
  float sum = 0.0f;
  for (int k = t; k < KP; k += 1024) sum += expf(pn[k] - m);
  red[t] = sum; __syncthreads();
  for (int o = 512; o; o >>= 1) { if (t < o) red[t] += red[t + o]; __syncthreads(); }
  float lse = m + logf(red[0]);
  for (int k = t; k < KP; k += 1024) {
    float v = pn[k] - lse;
    p1out[k] = v;
    wexp[k] = expf(v);
  }
}

// ---------------- gather h1 + per-block partial weighted sums --------------
__global__ __launch_bounds__(256) void gather_kernel(
    const float* __restrict__ h1pre, const int* __restrict__ idx,
    const float* __restrict__ wexp, float* __restrict__ h1out,
    float* __restrict__ partials) {
  int t = threadIdx.x;
  int k0 = blockIdx.x * 64;
  float part[4] = {0.f, 0.f, 0.f, 0.f};
  for (int kk = 0; kk < 64; ++kk) {
    int k = k0 + kk;
    int src = idx[k];
    float w = wexp[k];
#pragma unroll
    for (int c = 0; c < 4; ++c) {
      float v = h1pre[(size_t)src * HD + t + c * 256];
      h1out[(size_t)k * HD + t + c * 256] = v;
      part[c] = fmaf(w, v, part[c]);
    }
  }
#pragma unroll
  for (int c = 0; c < 4; ++c) partials[(size_t)blockIdx.x * HD + t + c * 256] = part[c];
}

__global__ __launch_bounds__(256) void reduce_mean_kernel(
    const float* __restrict__ partials, float* __restrict__ mean_hid) {
  int j = blockIdx.x * 256 + threadIdx.x;
  float s = 0.0f;
  for (int b = 0; b < 256; ++b) s += partials[(size_t)b * HD + j];
  mean_hid[j] = s;
}

// ---------------- final 2-layer head ---------------------------------------
__global__ __launch_bounds__(64) void final_kernel(
    const float* __restrict__ mean_hid,
    const float* __restrict__ wh1, const float* __restrict__ bh1,
    const float* __restrict__ wh2, const float* __restrict__ bh2,
    float* __restrict__ out) {
  __shared__ float hrelu[24];
  int t = threadIdx.x;
  if (t < 24) {
    float s = bh1[t];
    for (int i = 0; i < HD; ++i) s = fmaf(mean_hid[i], wh1[i * 24 + t], s);
    hrelu[t] = fmaxf(s, 0.0f);
  }
  __syncthreads();
  if (t < 2) {
    float s = bh2[t];
    for (int j = 0; j < 24; ++j) s = fmaf(hrelu[j], wh2[j * 2 + t], s);
    out[t] = s;
  }
}

extern "C" void kernel_launch(void* const* d_in, const int* in_sizes, int n_in,
                              void* d_out, int out_size, void* d_ws, size_t ws_size,
                              hipStream_t stream) {
  (void)in_sizes; (void)n_in; (void)out_size; (void)ws_size;
  const float* input_ = (const float*)d_in[0];
  const float* h0    = (const float*)d_in[1];
  const float* p0    = (const float*)d_in[2];
  const float* eps   = (const float*)d_in[3];
  const float* w_z   = (const float*)d_in[4];
  const float* b_z   = (const float*)d_in[5];
  const float* w_r   = (const float*)d_in[6];
  const float* b_r   = (const float*)d_in[7];
  const float* w_n   = (const float*)d_in[8];
  const float* b_n   = (const float*)d_in[9];
  const float* w_obs = (const float*)d_in[10];
  const float* b_obs = (const float*)d_in[11];
  const float* w_h1  = (const float*)d_in[12];
  const float* b_h1  = (const float*)d_in[13];
  const float* w_h2  = (const float*)d_in[14];
  const float* b_h2  = (const float*)d_in[15];

  float* out = (float*)d_out;
  float* out_loc = out;                       // 2
  float* out_h1  = out + 2;                   // KP*HD (z scratch, then final h1)
  float* out_p1  = out + 2 + (size_t)KP * HD; // KP

  // workspace layout (halfs first, then floats)
  _Float16* rhh  = (_Float16*)d_ws;                 // KP*HD halfs
  _Float16* rhl  = rhh + (size_t)KP * HD;           // KP*HD halfs
  float* h1pre   = (float*)(rhl + (size_t)KP * HD); // KP*HD floats
  float* zb      = h1pre + (size_t)KP * HD;         // 1024
  float* rb      = zb + 1024;                       // 1024
  float* nb      = rb + 1024;                       // 2048
  float* ob      = nb + 2048;                       // [0]=obs bias, [8]=Lmax
  float* sbuf    = ob + 16;                         // KP
  float* p1v     = sbuf + KP;                       // KP
  float* logits  = p1v + KP;                        // KP
  float* pn      = logits + KP;                     // KP
  float* wexpb   = pn + KP;                         // KP
  float* mean_hid= wexpb + KP;                      // 1024
  float* partials= mean_hid + 1024;                 // 256*1024
  int*   idxb    = (int*)(partials + 256 * HD);     // KP ints
  uint32_t* sthrb = (uint32_t*)(idxb + KP);         // 16384 u32
  unsigned long long* bestb = (unsigned long long*)(sthrb + KP); // 16384 u64
  int*   hotcb   = (int*)(bestb + KP);              // HOTCAP ints
  unsigned int* hotnb = (unsigned int*)(hotcb + HOTCAP); // 1 (pad 16)
  _Float16* wt   = (_Float16*)(hotnb + 16);         // 8M halfs
  _Float16* wzHi = wt;
  _Float16* wzLo = wt + 1 * (size_t)HD * HD;
  _Float16* wrHi = wt + 2 * (size_t)HD * HD;
  _Float16* wrLo = wt + 3 * (size_t)HD * HD;
  _Float16* wmHi = wt + 4 * (size_t)HD * HD;
  _Float16* wmLo = wt + 5 * (size_t)HD * HD;
  _Float16* wvHi = wt + 6 * (size_t)HD * HD;
  _Float16* wvLo = wt + 7 * (size_t)HD * HD;

  bias_kernel<<<17, 256, 0, stream>>>(input_, w_z, b_z, w_r, b_r, w_n, b_n,
                                      w_obs, b_obs, zb, rb, nb, ob);

  dim3 gs(32, 32, 4);
  splitw_kernel<<<gs, 256, 0, stream>>>(w_z, w_r, w_n, wzHi, wzLo, wrHi, wrLo,
                                        wmHi, wmLo, wvHi, wvLo);

  dim3 g1(KP / 128, HD / 64);
  gemm_zr_mfma<<<g1, 256, 0, stream>>>(h0, wzHi, wzLo, wrHi, wrLo, zb, rb,
                                       out_h1 /*z*/, rhh, rhl);

  gemm_n_mfma<<<g1, 256, 0, stream>>>(rhh, rhl, wmHi, wmLo, wvHi, wvLo, nb,
                                      h0, eps, out_h1 /*z*/, h1pre);

  score_kernel<<<KP / 4, 256, 0, stream>>>(h1pre, w_obs, ob, p0, sbuf);

  softmax_kernel<<<1, 1024, 0, stream>>>(sbuf, p1v, logits, ob + 8, hotcb, hotnb);

  thr_kernel<<<KP / 4, 256, 0, stream>>>(logits, ob + 8, hotcb, hotnb, sthrb, bestb);

  scan_kernel<<<KP, 256, 0, stream>>>(sthrb, logits, bestb, idxb);

  resample_kernel<<<1, 1024, 0, stream>>>(p1v, idxb, pn, out_p1, wexpb);

  gather_kernel<<<KP / 64, 256, 0, stream>>>(h1pre, idxb, wexpb, out_h1, partials);

  reduce_mean_kernel<<<4, 256, 0, stream>>>(partials, mean_hid);

  final_kernel<<<1, 64, 0, stream>>>(mean_hid, w_h1, b_h1, w_h2, b_h2, out_loc);
}

// Round 10
// 1249.089 us; speedup vs baseline: 1.1458x; 1.1458x over previous
//
#include <hip/hip_runtime.h>
#include <math.h>
#include <stdint.h>

#define KP 16384
#define IN_DIM 512
#define HD 1024
#define WQ 512      // per-wave LDS survivor queue
#define HOTCAP 1024

typedef _Float16 f16x8 __attribute__((ext_vector_type(8)));
typedef float f32x4 __attribute__((ext_vector_type(4)));

// ---------------- threefry2x32 (JAX key(42) => k0=0, k1=42) ----------------
__device__ __forceinline__ uint32_t rotl(uint32_t x, uint32_t r) {
  return __builtin_amdgcn_alignbit(x, x, 32u - r);
}

// cipher specialized for x0_init=0; input v = i + 42 (= x1 after key add)
__device__ __forceinline__ uint32_t tf_bits(uint32_t x1) {
  const uint32_t ks1 = 42u, ks2 = 42u ^ 0x1BD11BDAu;
  uint32_t x0 = x1;                       // x0(=0) += x1
  x1 = rotl(x1, 13) ^ x0;
  x0 += x1; x1 = rotl(x1, 15) ^ x0;
  x0 += x1; x1 = rotl(x1, 26) ^ x0;
  x0 += x1; x1 = rotl(x1, 6)  ^ x0;
  x0 += ks1; x1 += ks2 + 1u;
  x0 += x1; x1 = rotl(x1, 17) ^ x0;
  x0 += x1; x1 = rotl(x1, 29) ^ x0;
  x0 += x1; x1 = rotl(x1, 16) ^ x0;
  x0 += x1; x1 = rotl(x1, 24) ^ x0;
  x0 += ks2; x1 += 2u;
  x0 += x1; x1 = rotl(x1, 13) ^ x0;
  x0 += x1; x1 = rotl(x1, 15) ^ x0;
  x0 += x1; x1 = rotl(x1, 26) ^ x0;
  x0 += x1; x1 = rotl(x1, 6)  ^ x0;
  x1 += ks1 + 3u;
  x0 += x1; x1 = rotl(x1, 17) ^ x0;
  x0 += x1; x1 = rotl(x1, 29) ^ x0;
  x0 += x1; x1 = rotl(x1, 16) ^ x0;
  x0 += x1; x1 = rotl(x1, 24) ^ x0;
  x0 += ks1; x1 += ks2 + 4u;
  x0 += x1; x1 = rotl(x1, 13) ^ x0;
  x0 += x1; x1 = rotl(x1, 15) ^ x0;
  x0 += x1; x1 = rotl(x1, 26) ^ x0;
  x0 += x1; x1 = rotl(x1, 6)  ^ x0;
  x0 += ks2; x1 += 5u;
  return x0 ^ x1;
}

__device__ __forceinline__ float gumbel_from_bits(uint32_t b) {
  uint32_t ub = (b >> 9) | 0x3f800000u;
  float u = __uint_as_float(ub) - 1.0f;
  u = fmaxf(u, 1.1754943508222875e-38f);
  return -logf(-logf(u));
}

// monotone (g, smaller-c-wins) -> uint64 key for max-reduce argmax
__device__ __forceinline__ unsigned long long pack_key(float g, int c) {
  uint32_t u = __float_as_uint(g);
  u = (u & 0x80000000u) ? ~u : (u | 0x80000000u);
  return ((unsigned long long)u << 32) | (uint32_t)(16383 - c);
}

// ---------------- bias precompute: input_ @ W[1024:,:] + b ----------------
__global__ __launch_bounds__(256) void bias_kernel(
    const float* __restrict__ in,
    const float* __restrict__ wz, const float* __restrict__ bz,
    const float* __restrict__ wr, const float* __restrict__ br,
    const float* __restrict__ wn, const float* __restrict__ bn,
    const float* __restrict__ wobs, const float* __restrict__ bobs,
    float* __restrict__ zb, float* __restrict__ rb,
    float* __restrict__ nb, float* __restrict__ ob) {
  __shared__ float sin_[IN_DIM];
  int t = threadIdx.x;
  for (int i = t; i < IN_DIM; i += 256) sin_[i] = in[i];
  __syncthreads();
  int gid = blockIdx.x * 256 + t;
  if (gid < 1024) {
    float s = bz[gid];
    for (int i = 0; i < IN_DIM; ++i) s = fmaf(sin_[i], wz[(HD + i) * HD + gid], s);
    zb[gid] = s;
  } else if (gid < 2048) {
    int j = gid - 1024;
    float s = br[j];
    for (int i = 0; i < IN_DIM; ++i) s = fmaf(sin_[i], wr[(HD + i) * HD + j], s);
    rb[j] = s;
  } else if (gid < 4096) {
    int j = gid - 2048;
    float s = bn[j];
    for (int i = 0; i < IN_DIM; ++i) s = fmaf(sin_[i], wn[(HD + i) * 2048 + j], s);
    nb[j] = s;
  } else if (gid == 4096) {
    float s = bobs[0];
    for (int i = 0; i < IN_DIM; ++i) s = fmaf(sin_[i], wobs[HD + i], s);
    ob[0] = s;
  }
}

// ---------------- weight transpose + fp16 2-term split (x64 prescale) ------
__global__ __launch_bounds__(256) void splitw_kernel(
    const float* __restrict__ wz, const float* __restrict__ wr,
    const float* __restrict__ wn,
    _Float16* __restrict__ zHi, _Float16* __restrict__ zLo,
    _Float16* __restrict__ rHi, _Float16* __restrict__ rLo,
    _Float16* __restrict__ mHi, _Float16* __restrict__ mLo,
    _Float16* __restrict__ vHi, _Float16* __restrict__ vLo) {
  __shared__ float tile[32][33];
  int m = blockIdx.z;
  const float* src; int ld, cofs; _Float16 *oh, *ol;
  if (m == 0)      { src = wz; ld = 1024; cofs = 0;    oh = zHi; ol = zLo; }
  else if (m == 1) { src = wr; ld = 1024; cofs = 0;    oh = rHi; ol = rLo; }
  else if (m == 2) { src = wn; ld = 2048; cofs = 0;    oh = mHi; ol = mLo; }
  else             { src = wn; ld = 2048; cofs = 1024; oh = vHi; ol = vLo; }
  int k0 = blockIdx.x * 32, n0 = blockIdx.y * 32;
  int tx = threadIdx.x & 31, ty = threadIdx.x >> 5;
#pragma unroll
  for (int i = 0; i < 4; ++i) {
    int k = ty * 4 + i;
    tile[k][tx] = src[(size_t)(k0 + k) * ld + cofs + n0 + tx];
  }
  __syncthreads();
#pragma unroll
  for (int i = 0; i < 4; ++i) {
    int n = ty * 4 + i;
    float v = tile[tx][n] * 64.0f;
    _Float16 h = (_Float16)v;
    _Float16 l = (_Float16)((v - (float)h) * 2048.0f);
    oh[(size_t)(n0 + n) * 1024 + k0 + tx] = h;
    ol[(size_t)(n0 + n) * 1024 + k0 + tx] = l;
  }
}

// ---------------- MFMA split-GEMM #1: z & rh (rh written as fp16 split) ----
#define LDH 40   // halfs per LDS row (32 data + 8 pad); 80B, 16B-multiple

__global__ __launch_bounds__(256, 2) void gemm_zr_mfma(
    const float* __restrict__ A,  // h0: KP x HD fp32 (also epilogue h0)
    const _Float16* __restrict__ BzHi, const _Float16* __restrict__ BzLo,
    const _Float16* __restrict__ BrHi, const _Float16* __restrict__ BrLo,
    const float* __restrict__ zbias, const float* __restrict__ rbias,
    float* __restrict__ zout,
    _Float16* __restrict__ rhh, _Float16* __restrict__ rhl) {
  __shared__ __align__(16) _Float16 Ah[128 * LDH], Al[128 * LDH];
  __shared__ __align__(16) _Float16 B0h[64 * LDH], B0l[64 * LDH];
  __shared__ __align__(16) _Float16 B1h[64 * LDH], B1l[64 * LDH];
  int t = threadIdx.x;
  int row0 = blockIdx.x * 128, col0 = blockIdx.y * 64;
  int wave = t >> 6, lane = t & 63;
  int lr = lane & 15, hh = lane >> 4;
  int WR = (wave >> 1) * 64, WC = (wave & 1) * 32;

  f32x4 acc0[4][2][2] = {};
  f32x4 acc1[4][2][2] = {};

  for (int kb = 0; kb < 1024; kb += 32) {
#pragma unroll
    for (int p = 0; p < 2; ++p) {
      int id = t + p * 256;
      int row = id >> 2, kc = id & 3;
      const float* g = &A[(size_t)(row0 + row) * 1024 + kb + kc * 8];
      float4 v0 = *(const float4*)g;
      float4 v1 = *(const float4*)(g + 4);
      float vv[8] = {v0.x, v0.y, v0.z, v0.w, v1.x, v1.y, v1.z, v1.w};
      f16x8 hi, lo;
#pragma unroll
      for (int j = 0; j < 8; ++j) {
        _Float16 h = (_Float16)vv[j];
        hi[j] = h;
        lo[j] = (_Float16)((vv[j] - (float)h) * 2048.0f);
      }
      *(f16x8*)&Ah[row * LDH + kc * 8] = hi;
      *(f16x8*)&Al[row * LDH + kc * 8] = lo;
    }
    {
      int n = t >> 2, kc = t & 3;
      size_t gofs = (size_t)(col0 + n) * 1024 + kb + kc * 8;
      int lofs = n * LDH + kc * 8;
      *(f16x8*)&B0h[lofs] = *(const f16x8*)&BzHi[gofs];
      *(f16x8*)&B0l[lofs] = *(const f16x8*)&BzLo[gofs];
      *(f16x8*)&B1h[lofs] = *(const f16x8*)&BrHi[gofs];
      *(f16x8*)&B1l[lofs] = *(const f16x8*)&BrLo[gofs];
    }
    __syncthreads();
    f16x8 ah[4], al[4], bh[2][2], bl[2][2];
#pragma unroll
    for (int mt = 0; mt < 4; ++mt) {
      int r = WR + mt * 16 + lr;
      ah[mt] = *(f16x8*)&Ah[r * LDH + hh * 8];
      al[mt] = *(f16x8*)&Al[r * LDH + hh * 8];
    }
#pragma unroll
    for (int nt = 0; nt < 2; ++nt) {
      int c = WC + nt * 16 + lr;
      bh[0][nt] = *(f16x8*)&B0h[c * LDH + hh * 8];
      bl[0][nt] = *(f16x8*)&B0l[c * LDH + hh * 8];
      bh[1][nt] = *(f16x8*)&B1h[c * LDH + hh * 8];
      bl[1][nt] = *(f16x8*)&B1l[c * LDH + hh * 8];
    }
#pragma unroll
    for (int mt = 0; mt < 4; ++mt)
#pragma unroll
      for (int nt = 0; nt < 2; ++nt)
#pragma unroll
        for (int m = 0; m < 2; ++m) {
          acc0[mt][nt][m] = __builtin_amdgcn_mfma_f32_16x16x32_f16(ah[mt], bh[m][nt], acc0[mt][nt][m], 0, 0, 0);
          acc1[mt][nt][m] = __builtin_amdgcn_mfma_f32_16x16x32_f16(ah[mt], bl[m][nt], acc1[mt][nt][m], 0, 0, 0);
          acc1[mt][nt][m] = __builtin_amdgcn_mfma_f32_16x16x32_f16(al[mt], bh[m][nt], acc1[mt][nt][m], 0, 0, 0);
        }
    __syncthreads();
  }
  const float INV = 1.0f / 2048.0f, WS = 1.0f / 64.0f;
#pragma unroll
  for (int mt = 0; mt < 4; ++mt)
#pragma unroll
    for (int nt = 0; nt < 2; ++nt) {
      int col = col0 + WC + nt * 16 + lr;
#pragma unroll
      for (int q = 0; q < 4; ++q) {
        int row = row0 + WR + mt * 16 + hh * 4 + q;
        size_t off = (size_t)row * 1024 + col;
        float vz = (acc0[mt][nt][0][q] + acc1[mt][nt][0][q] * INV) * WS + zbias[col];
        float vr = (acc0[mt][nt][1][q] + acc1[mt][nt][1][q] * INV) * WS + rbias[col];
        float z = 1.0f / (1.0f + expf(-vz));
        float r = 1.0f / (1.0f + expf(-vr));
        float rv = r * A[off];
        zout[off] = z;
        _Float16 rhi = (_Float16)rv;
        rhh[off] = rhi;
        rhl[off] = (_Float16)((rv - (float)rhi) * 2048.0f);
      }
    }
}

// ---------------- MFMA split-GEMM #2: A pre-split fp16; h1 epilogue --------
__global__ __launch_bounds__(256, 2) void gemm_n_mfma(
    const _Float16* __restrict__ Ahg, const _Float16* __restrict__ Alg, // rh split
    const _Float16* __restrict__ BmHi, const _Float16* __restrict__ BmLo,
    const _Float16* __restrict__ BvHi, const _Float16* __restrict__ BvLo,
    const float* __restrict__ nbias,
    const float* __restrict__ h0, const float* __restrict__ eps,
    const float* __restrict__ zbuf, float* __restrict__ h1out) {
  __shared__ __align__(16) _Float16 Ah[128 * LDH], Al[128 * LDH];
  __shared__ __align__(16) _Float16 B0h[64 * LDH], B0l[64 * LDH];
  __shared__ __align__(16) _Float16 B1h[64 * LDH], B1l[64 * LDH];
  int t = threadIdx.x;
  int row0 = blockIdx.x * 128, col0 = blockIdx.y * 64;
  int wave = t >> 6, lane = t & 63;
  int lr = lane & 15, hh = lane >> 4;
  int WR = (wave >> 1) * 64, WC = (wave & 1) * 32;

  f32x4 acc0[4][2][2] = {};
  f32x4 acc1[4][2][2] = {};

  for (int kb = 0; kb < 1024; kb += 32) {
#pragma unroll
    for (int p = 0; p < 2; ++p) {
      int id = t + p * 256;
      int row = id >> 2, kc = id & 3;
      size_t g = (size_t)(row0 + row) * 1024 + kb + kc * 8;
      int lofs = row * LDH + kc * 8;
      *(f16x8*)&Ah[lofs] = *(const f16x8*)&Ahg[g];
      *(f16x8*)&Al[lofs] = *(const f16x8*)&Alg[g];
    }
    {
      int n = t >> 2, kc = t & 3;
      size_t gofs = (size_t)(col0 + n) * 1024 + kb + kc * 8;
      int lofs = n * LDH + kc * 8;
      *(f16x8*)&B0h[lofs] = *(const f16x8*)&BmHi[gofs];
      *(f16x8*)&B0l[lofs] = *(const f16x8*)&BmLo[gofs];
      *(f16x8*)&B1h[lofs] = *(const f16x8*)&BvHi[gofs];
      *(f16x8*)&B1l[lofs] = *(const f16x8*)&BvLo[gofs];
    }
    __syncthreads();
    f16x8 ah[4], al[4], bh[2][2], bl[2][2];
#pragma unroll
    for (int mt = 0; mt < 4; ++mt) {
      int r = WR + mt * 16 + lr;
      ah[mt] = *(f16x8*)&Ah[r * LDH + hh * 8];
      al[mt] = *(f16x8*)&Al[r * LDH + hh * 8];
    }
#pragma unroll
    for (int nt = 0; nt < 2; ++nt) {
      int c = WC + nt * 16 + lr;
      bh[0][nt] = *(f16x8*)&B0h[c * LDH + hh * 8];
      bl[0][nt] = *(f16x8*)&B0l[c * LDH + hh * 8];
      bh[1][nt] = *(f16x8*)&B1h[c * LDH + hh * 8];
      bl[1][nt] = *(f16x8*)&B1l[c * LDH + hh * 8];
    }
#pragma unroll
    for (int mt = 0; mt < 4; ++mt)
#pragma unroll
      for (int nt = 0; nt < 2; ++nt)
#pragma unroll
        for (int m = 0; m < 2; ++m) {
          acc0[mt][nt][m] = __builtin_amdgcn_mfma_f32_16x16x32_f16(ah[mt], bh[m][nt], acc0[mt][nt][m], 0, 0, 0);
          acc1[mt][nt][m] = __builtin_amdgcn_mfma_f32_16x16x32_f16(ah[mt], bl[m][nt], acc1[mt][nt][m], 0, 0, 0);
          acc1[mt][nt][m] = __builtin_amdgcn_mfma_f32_16x16x32_f16(al[mt], bh[m][nt], acc1[mt][nt][m], 0, 0, 0);
        }
    __syncthreads();
  }
  const float INV = 1.0f / 2048.0f, WS = 1.0f / 64.0f;
#pragma unroll
  for (int mt = 0; mt < 4; ++mt)
#pragma unroll
    for (int nt = 0; nt < 2; ++nt) {
      int col = col0 + WC + nt * 16 + lr;
#pragma unroll
      for (int q = 0; q < 4; ++q) {
        int row = row0 + WR + mt * 16 + hh * 4 + q;
        size_t off = (size_t)row * 1024 + col;
        float mu = (acc0[mt][nt][0][q] + acc1[mt][nt][0][q] * INV) * WS + nbias[col];
        float var = (acc0[mt][nt][1][q] + acc1[mt][nt][1][q] * INV) * WS + nbias[1024 + col];
        float sp = fmaxf(var, 0.0f) + log1pf(expf(-fabsf(var)));
        float n = tanhf(mu + eps[off] * sp);
        float z = zbuf[off];
        h1out[off] = (1.0f - z) * n + z * h0[off];
      }
    }
}

// ---------------- score: s = h1@wobs[:1024] + ob + p0 ----------------------
__global__ __launch_bounds__(256) void score_kernel(
    const float* __restrict__ h1, const float* __restrict__ wobs,
    const float* __restrict__ ob, const float* __restrict__ p0,
    float* __restrict__ s) {
  __shared__ float w[HD];
  int t = threadIdx.x;
  for (int i = t; i < HD; i += 256) w[i] = wobs[i];
  __syncthreads();
  int wave = t >> 6, lane = t & 63;
  int row = blockIdx.x * 4 + wave;
  float acc = 0.0f;
  for (int c = lane * 4; c < HD; c += 256) {
    float4 v = *(const float4*)&h1[(size_t)row * HD + c];
    acc = fmaf(v.x, w[c], acc);
    acc = fmaf(v.y, w[c + 1], acc);
    acc = fmaf(v.z, w[c + 2], acc);
    acc = fmaf(v.w, w[c + 3], acc);
  }
#pragma unroll
  for (int off = 32; off; off >>= 1) acc += __shfl_down(acc, off);
  if (lane == 0) s[row] = acc + ob[0] + p0[row];
}

// -- log_softmax + categorical logits + Lmax + DETERMINISTIC hot list -------
// 1 block, 1024 threads; thread t owns contiguous columns [t*16, t*16+16).
// Hot threshold chosen adaptively (deepest of Lmax-{2..10} with count<=cap);
// compaction via block prefix scan -> column-ordered, replay-invariant.
__global__ __launch_bounds__(1024) void softmax_kernel(
    const float* __restrict__ s, float* __restrict__ p1v,
    float* __restrict__ logits, float* __restrict__ lmaxp,
    int* __restrict__ hotc, unsigned int* __restrict__ hotn) {
  __shared__ float red[1024];
  __shared__ int sc[1024];
  __shared__ float sh_thr;
  int t = threadIdx.x;
  float m = -INFINITY;
  for (int k = t; k < KP; k += 1024) m = fmaxf(m, s[k]);
  red[t] = m; __syncthreads();
  for (int o = 512; o; o >>= 1) { if (t < o) red[t] = fmaxf(red[t], red[t + o]); __syncthreads(); }
  m = red[0]; __syncthreads();
  float sum = 0.0f;
  for (int k = t; k < KP; k += 1024) sum += expf(s[k] - m);
  red[t] = sum; __syncthreads();
  for (int o = 512; o; o >>= 1) { if (t < o) red[t] += red[t + o]; __syncthreads(); }
  float ls = logf(red[0]);
  float lmax = logf(0.5f * expf(-ls) + (0.5f / KP));

  float lg[16];
#pragma unroll
  for (int j = 0; j < 16; ++j) {
    int k = t * 16 + j;
    float p = s[k] - m - ls;
    p1v[k] = p;
    lg[j] = logf(0.5f * expf(p) + (0.5f / KP));
    logits[k] = lg[j];
  }
  // adaptive deterministic threshold: deepest depth with count <= HOTCAP
  float chosen = INFINITY;
#pragma unroll
  for (int d = 2; d <= 10; d += 2) {
    float cand = lmax - (float)d;
    int cnt = 0;
#pragma unroll
    for (int j = 0; j < 16; ++j) cnt += (lg[j] > cand) ? 1 : 0;
    sc[t] = cnt; __syncthreads();
    for (int o = 512; o; o >>= 1) { if (t < o) sc[t] += sc[t + o]; __syncthreads(); }
    int total = sc[0]; __syncthreads();
    if (total <= HOTCAP) chosen = cand;   // uniform across block
  }
  if (t == 0) sh_thr = chosen;
  __syncthreads();
  float hthr = sh_thr;
  // column-ordered compaction via inclusive block scan
  int mycnt = 0;
#pragma unroll
  for (int j = 0; j < 16; ++j) mycnt += (lg[j] > hthr) ? 1 : 0;
  sc[t] = mycnt; __syncthreads();
  for (int o = 1; o < 1024; o <<= 1) {
    int v = (t >= o) ? sc[t - o] : 0;
    __syncthreads();
    sc[t] += v;
    __syncthreads();
  }
  int ofs = sc[t] - mycnt;
#pragma unroll
  for (int j = 0; j < 16; ++j) {
    if (lg[j] > hthr) hotc[ofs++] = t * 16 + j;
  }
  if (t == 1023) hotn[0] = (unsigned int)sc[1023];
  if (t == 0) lmaxp[0] = lmax;
}

// ---------------- categorical phase A: sample + hot list -> threshold ------
// one wave per row; exact eval of cols 0..255 and hot-list cols
__global__ __launch_bounds__(256) void thr_kernel(
    const float* __restrict__ logits, const float* __restrict__ lmaxp,
    const int* __restrict__ hotc, const unsigned int* __restrict__ hotn,
    uint32_t* __restrict__ sthr, unsigned long long* __restrict__ best) {
  int t = threadIdx.x;
  int wave = t >> 6, lane = t & 63;
  int r = blockIdx.x * 4 + wave;
  uint32_t base = ((uint32_t)r << 14) + 42u;

  unsigned long long key = 0ull;
#pragma unroll
  for (int j = 0; j < 4; ++j) {
    int c = lane + j * 64;
    uint32_t bits = tf_bits(base + (uint32_t)c);
    float g = gumbel_from_bits(bits) + logits[c];
    unsigned long long k2 = pack_key(g, c);
    if (k2 > key) key = k2;
  }
  int hn = (int)hotn[0];
  if (hn > HOTCAP) hn = HOTCAP;
  for (int i = lane; i < hn; i += 64) {
    int c = hotc[i];
    uint32_t bits = tf_bits(base + (uint32_t)c);
    float g = gumbel_from_bits(bits) + logits[c];
    unsigned long long k2 = pack_key(g, c);
    if (k2 > key) key = k2;
  }
#pragma unroll
  for (int off = 32; off; off >>= 1) {
    unsigned long long ok = __shfl_down(key, off);
    if (ok > key) key = ok;
  }
  if (lane == 0) {
    uint32_t u = (uint32_t)(key >> 32);
    u = (u & 0x80000000u) ? (u & 0x7FFFFFFFu) : ~u;
    float B0 = __uint_as_float(u);
    float wth = expf(lmaxp[0] + 1e-3f - B0);
    float omu = -expm1f(-wth);
    float delta = 8388608.0f * omu;
    uint32_t thr;
    if (delta >= 8388592.0f) thr = 0u;
    else {
      thr = 8388608u - (uint32_t)delta;
      thr = (thr > 24u) ? (thr - 24u) : 0u;
    }
    sthr[r] = thr << 9;   // compare raw bits directly
    best[r] = key;
  }
}

// ---------------- categorical phase B: ILP-4 scan, ballot wave queues ------
// 4096 blocks x 256 threads; block owns rows 4b..4b+3. 4 independent ciphers
// per thread-iteration; survivors ballot-compacted into per-wave LDS queues
// (no atomics, no VMEM in loop); deferred batch eval; fused decode.
__global__ __launch_bounds__(256) void scan_kernel(
    const uint32_t* __restrict__ sthr, const float* __restrict__ logits,
    const unsigned long long* __restrict__ best, int* __restrict__ idx) {
  __shared__ uint32_t qb[4][WQ];
  __shared__ uint32_t qc[4][WQ];
  __shared__ unsigned long long redw[4];
  int t = threadIdx.x;
  int wave = t >> 6, lane = t & 63;
  unsigned long long lmask = (1ull << lane) - 1ull;

  for (int j = 0; j < 4; ++j) {
    int r = blockIdx.x * 4 + j;
    uint32_t thr = sthr[r];
    uint32_t base = ((uint32_t)r << 14) + 42u;
    unsigned long long mykey = 0ull;
    int wcnt = 0;
#pragma unroll 2
    for (int k = 0; k < 16; ++k) {
      uint32_t c0 = (uint32_t)k * 1024u + (uint32_t)t * 4u;
      uint32_t v0 = base + c0;
      uint32_t b0 = tf_bits(v0);
      uint32_t b1 = tf_bits(v0 + 1u);
      uint32_t b2 = tf_bits(v0 + 2u);
      uint32_t b3 = tf_bits(v0 + 3u);
#define QPUSH(bits, cc) {                                                 \
      bool pass = (bits) >= thr;                                          \
      unsigned long long mb = __ballot(pass);                             \
      if (mb) {                                                           \
        if (pass) {                                                       \
          int slot = wcnt + __popcll(mb & lmask);                         \
          if (slot < WQ) { qb[wave][slot] = (bits); qc[wave][slot] = (cc); } \
          else { float g = gumbel_from_bits(bits) + logits[cc];           \
                 unsigned long long kk = pack_key(g, (int)(cc));          \
                 if (kk > mykey) mykey = kk; }                            \
        }                                                                 \
        wcnt += __popcll(mb); } }
      QPUSH(b0, c0)
      QPUSH(b1, c0 + 1u)
      QPUSH(b2, c0 + 2u)
      QPUSH(b3, c0 + 3u)
#undef QPUSH
    }
    // deferred exact eval of this wave's queue
    int n = wcnt < WQ ? wcnt : WQ;
    for (int i = lane; i < n; i += 64) {
      float g = gumbel_from_bits(qb[wave][i]) + logits[qc[wave][i]];
      unsigned long long kk = pack_key(g, (int)qc[wave][i]);
      if (kk > mykey) mykey = kk;
    }
#pragma unroll
    for (int off = 32; off; off >>= 1) {
      unsigned long long ok = __shfl_down(mykey, off);
      if (ok > mykey) mykey = ok;
    }
    if (lane == 0) redw[wave] = mykey;
    __syncthreads();
    if (t == 0) {
      unsigned long long k2 = best[r];   // block owns row r exclusively
      for (int w = 0; w < 4; ++w) if (redw[w] > k2) k2 = redw[w];
      idx[r] = 16383 - (int)(k2 & 16383ull);
    }
    __syncthreads();
  }
}

// ---------------- resample weights + final p1 ------------------------------
__global__ __launch_bounds__(1024) void resample_kernel(
    const float* __restrict__ p1v, const int* __restrict__ idx,
    float* __restrict__ pn, float* __restrict__ p1out, float* __restrict__ wexp) {
  __shared__ float red[1024];
  int t = threadIdx.x;
  float m = -INFINITY;
  for (int k = t; k < KP; k += 1024) {
    float pv = p1v[idx[k]];
    float w = expf(pv);
    float v = logf(w / (0.5f * w + (0.5f / KP)));
    pn[k] = v;
    m = fmaxf(m, v);
  }
  red[t] = m; __syncthreads();
  for (int o = 512; o; o >>= 1) { if (t < o) red[t] = fmaxf(red[t], red[t + o]); __syncthreads(); }
  m = red[0]; __syncthreads();
  float sum = 0.0f;
  for (int k = t; k < KP; k += 1024) sum += expf(pn[k] - m);
  red[t] = sum; __syncthreads();
  for (int o = 512; o; o >>= 1) { if (t < o) red[t] += red[t + o]; __syncthreads(); }
  float lse = m + logf(red[0]);
  for (int k = t; k < KP; k += 1024) {
    float v = pn[k] - lse;
    p1out[k] = v;
    wexp[k] = expf(v);
  }
}

// ---------------- gather h1 + per-block partial weighted sums --------------
__global__ __launch_bounds__(256) void gather_kernel(
    const float* __restrict__ h1pre, const int* __restrict__ idx,
    const float* __restrict__ wexp, float* __restrict__ h1out,
    float* __restrict__ partials) {
  int t = threadIdx.x;
  int k0 = blockIdx.x * 64;
  float part[4] = {0.f, 0.f, 0.f, 0.f};
  for (int kk = 0; kk < 64; ++kk) {
    int k = k0 + kk;
    int src = idx[k];
    float w = wexp[k];
#pragma unroll
    for (int c = 0; c < 4; ++c) {
      float v = h1pre[(size_t)src * HD + t + c * 256];
      h1out[(size_t)k * HD + t + c * 256] = v;
      part[c] = fmaf(w, v, part[c]);
    }
  }
#pragma unroll
  for (int c = 0; c < 4; ++c) partials[(size_t)blockIdx.x * HD + t + c * 256] = part[c];
}

__global__ __launch_bounds__(256) void reduce_mean_kernel(
    const float* __restrict__ partials, float* __restrict__ mean_hid) {
  int j = blockIdx.x * 256 + threadIdx.x;
  float s = 0.0f;
  for (int b = 0; b < 256; ++b) s += partials[(size_t)b * HD + j];
  mean_hid[j] = s;
}

// ---------------- final 2-layer head ---------------------------------------
__global__ __launch_bounds__(64) void final_kernel(
    const float* __restrict__ mean_hid,
    const float* __restrict__ wh1, const float* __restrict__ bh1,
    const float* __restrict__ wh2, const float* __restrict__ bh2,
    float* __restrict__ out) {
  __shared__ float hrelu[24];
  int t = threadIdx.x;
  if (t < 24) {
    float s = bh1[t];
    for (int i = 0; i < HD; ++i) s = fmaf(mean_hid[i], wh1[i * 24 + t], s);
    hrelu[t] = fmaxf(s, 0.0f);
  }
  __syncthreads();
  if (t < 2) {
    float s = bh2[t];
    for (int j = 0; j < 24; ++j) s = fmaf(hrelu[j], wh2[j * 2 + t], s);
    out[t] = s;
  }
}

extern "C" void kernel_launch(void* const* d_in, const int* in_sizes, int n_in,
                              void* d_out, int out_size, void* d_ws, size_t ws_size,
                              hipStream_t stream) {
  (void)in_sizes; (void)n_in; (void)out_size; (void)ws_size;
  const float* input_ = (const float*)d_in[0];
  const float* h0    = (const float*)d_in[1];
  const float* p0    = (const float*)d_in[2];
  const float* eps   = (const float*)d_in[3];
  const float* w_z   = (const float*)d_in[4];
  const float* b_z   = (const float*)d_in[5];
  const float* w_r   = (const float*)d_in[6];
  const float* b_r   = (const float*)d_in[7];
  const float* w_n   = (const float*)d_in[8];
  const float* b_n   = (const float*)d_in[9];
  const float* w_obs = (const float*)d_in[10];
  const float* b_obs = (const float*)d_in[11];
  const float* w_h1  = (const float*)d_in[12];
  const float* b_h1  = (const float*)d_in[13];
  const float* w_h2  = (const float*)d_in[14];
  const float* b_h2  = (const float*)d_in[15];

  float* out = (float*)d_out;
  float* out_loc = out;                       // 2
  float* out_h1  = out + 2;                   // KP*HD (z scratch, then final h1)
  float* out_p1  = out + 2 + (size_t)KP * HD; // KP

  // workspace layout (halfs first, then floats)
  _Float16* rhh  = (_Float16*)d_ws;                 // KP*HD halfs
  _Float16* rhl  = rhh + (size_t)KP * HD;           // KP*HD halfs
  float* h1pre   = (float*)(rhl + (size_t)KP * HD); // KP*HD floats
  float* zb      = h1pre + (size_t)KP * HD;         // 1024
  float* rb      = zb + 1024;                       // 1024
  float* nb      = rb + 1024;                       // 2048
  float* ob      = nb + 2048;                       // [0]=obs bias, [8]=Lmax
  float* sbuf    = ob + 16;                         // KP
  float* p1v     = sbuf + KP;                       // KP
  float* logits  = p1v + KP;                        // KP
  float* pn      = logits + KP;                     // KP
  float* wexpb   = pn + KP;                         // KP
  float* mean_hid= wexpb + KP;                      // 1024
  float* partials= mean_hid + 1024;                 // 256*1024
  int*   idxb    = (int*)(partials + 256 * HD);     // KP ints
  uint32_t* sthrb = (uint32_t*)(idxb + KP);         // 16384 u32
  unsigned long long* bestb = (unsigned long long*)(sthrb + KP); // 16384 u64
  int*   hotcb   = (int*)(bestb + KP);              // HOTCAP ints
  unsigned int* hotnb = (unsigned int*)(hotcb + HOTCAP); // 1 (pad 16)
  _Float16* wt   = (_Float16*)(hotnb + 16);         // 8M halfs
  _Float16* wzHi = wt;
  _Float16* wzLo = wt + 1 * (size_t)HD * HD;
  _Float16* wrHi = wt + 2 * (size_t)HD * HD;
  _Float16* wrLo = wt + 3 * (size_t)HD * HD;
  _Float16* wmHi = wt + 4 * (size_t)HD * HD;
  _Float16* wmLo = wt + 5 * (size_t)HD * HD;
  _Float16* wvHi = wt + 6 * (size_t)HD * HD;
  _Float16* wvLo = wt + 7 * (size_t)HD * HD;

  bias_kernel<<<17, 256, 0, stream>>>(input_, w_z, b_z, w_r, b_r, w_n, b_n,
                                      w_obs, b_obs, zb, rb, nb, ob);

  dim3 gs(32, 32, 4);
  splitw_kernel<<<gs, 256, 0, stream>>>(w_z, w_r, w_n, wzHi, wzLo, wrHi, wrLo,
                                        wmHi, wmLo, wvHi, wvLo);

  dim3 g1(KP / 128, HD / 64);
  gemm_zr_mfma<<<g1, 256, 0, stream>>>(h0, wzHi, wzLo, wrHi, wrLo, zb, rb,
                                       out_h1 /*z*/, rhh, rhl);

  gemm_n_mfma<<<g1, 256, 0, stream>>>(rhh, rhl, wmHi, wmLo, wvHi, wvLo, nb,
                                      h0, eps, out_h1 /*z*/, h1pre);

  score_kernel<<<KP / 4, 256, 0, stream>>>(h1pre, w_obs, ob, p0, sbuf);

  softmax_kernel<<<1, 1024, 0, stream>>>(sbuf, p1v, logits, ob + 8, hotcb, hotnb);

  thr_kernel<<<KP / 4, 256, 0, stream>>>(logits, ob + 8, hotcb, hotnb, sthrb, bestb);

  scan_kernel<<<4096, 256, 0, stream>>>(sthrb, logits, bestb, idxb);

  resample_kernel<<<1, 1024, 0, stream>>>(p1v, idxb, pn, out_p1, wexpb);

  gather_kernel<<<KP / 64, 256, 0, stream>>>(h1pre, idxb, wexpb, out_h1, partials);

  reduce_mean_kernel<<<4, 256, 0, stream>>>(partials, mean_hid);

  final_kernel<<<1, 64, 0, stream>>>(mean_hid, w_h1, b_h1, w_h2, b_h2, out_loc);
}